// Round 6
// baseline (288.919 us; speedup 1.0000x reference)
//
#include <hip/hip_runtime.h>

typedef __bf16 bf16_t;
typedef __bf16 bf16x8 __attribute__((ext_vector_type(8)));
typedef __bf16 bf16x4 __attribute__((ext_vector_type(4)));
typedef float  f32x4  __attribute__((ext_vector_type(4)));
typedef float  f32x16 __attribute__((ext_vector_type(16)));

#define PIX 196      // 14*14
#define P_  12544    // 16*28*28
#define M_  512

__device__ inline void gload_lds16(const void* g, void* l) {
  __builtin_amdgcn_global_load_lds((const __attribute__((address_space(1))) void*)g,
                                   (__attribute__((address_space(3))) void*)l,
                                   16, 0, 0);
}

// ---- conv_w [c][d][2][2] fp32 -> wtb bf16, fragment-native ----
__global__ __launch_bounds__(256) void k_wtb(const float* __restrict__ conv_w,
                                             bf16_t* __restrict__ wtb) {
  int c = blockIdx.x, d = threadIdx.x;
  f32x4 w = *reinterpret_cast<const f32x4*>(conv_w + (c * 256 + d) * 4);
  int ks = c >> 4, kb = (c >> 3) & 1, j = c & 7;
#pragma unroll
  for (int q = 0; q < 4; ++q) {
    int col = q * 256 + d;
    int cf = col >> 5;
    int lfrag = kb * 32 + (col & 31);
    wtb[((cf * 16 + ks) * 64 + lfrag) * 8 + j] = (bf16_t)w[q];
  }
}

// ---- x[n][c][hw] fp32 -> xb[p3=n*196+hw][c] bf16 (transpose via LDS) ----
__global__ __launch_bounds__(256) void k_xt(const float* __restrict__ x,
                                            bf16_t* __restrict__ xb) {
  __shared__ float xs[64][198];
  int n = blockIdx.x, c0 = blockIdx.y * 64;
  int t = threadIdx.x;
  const float* xp = x + (n * 256 + c0) * PIX;
#pragma unroll 7
  for (int r = 0; r < 49; ++r) {
    int idx = r * 256 + t;
    xs[idx / PIX][idx % PIX] = xp[idx];
  }
  __syncthreads();
  for (int r = 0; r < 13; ++r) {
    int idx = r * 256 + t;
    if (idx < 3136) {
      int hw = idx >> 4, c4 = idx & 15;
      bf16x4 h;
#pragma unroll
      for (int i = 0; i < 4; ++i) h[i] = (bf16_t)xs[c4 * 4 + i][hw];
      *reinterpret_cast<bf16x4*>(xb + (n * PIX + hw) * 256 + c0 + c4 * 4) = h;
    }
  }
}

// ---- ny -> fragment/LDS-native bf16 chunks + e_n = exp(-||ny||^2/2s^2)*alpha ----
__global__ __launch_bounds__(256) void k_nyprep(const float* __restrict__ ny,
                                                const float* __restrict__ alpha,
                                                const float* __restrict__ sigma,
                                                bf16_t* __restrict__ nys,
                                                float* __restrict__ e_n) {
  int l = threadIdx.x & 63;
  int row = blockIdx.x * 4 + (threadIdx.x >> 6);   // c*512+m, < 10240
  int c = row >> 9, m = row & 511;
  f32x4 v = *reinterpret_cast<const f32x4*>(ny + row * 256 + l * 4);
  bf16x4 h;
  float sq = 0.f;
#pragma unroll
  for (int i = 0; i < 4; ++i) {
    h[i] = (bf16_t)v[i];
    float fv = (float)h[i];
    sq += fv * fv;
  }
  int t = m >> 5, mr = m & 31;
  int ks = l >> 2, kb = (l >> 1) & 1, j0 = (l & 1) * 4;
  *reinterpret_cast<bf16x4*>(nys + ((c * 16 + t) * 16 + ks) * 512 + (kb * 32 + mr) * 8 + j0) = h;
#pragma unroll
  for (int o = 1; o < 64; o <<= 1) sq += __shfl_xor(sq, o);
  if (l == 0) {
    float s = sigma[0];
    e_n[row] = __expf(-sq / (2.f * s * s)) * alpha[row];
  }
}

// ---- conv as GEMM ----
__global__ __launch_bounds__(256) void k_convT(const bf16_t* __restrict__ xb,
                                               const bf16_t* __restrict__ wtb,
                                               const float* __restrict__ conv_b,
                                               const float* __restrict__ mean,
                                               const float* __restrict__ mean_norm,
                                               bf16_t* __restrict__ fb) {
  __shared__ bf16_t bs[32768];
  int rb = blockIdx.x * 64, cbase = blockIdx.y * 128;
  int tid = threadIdx.x, w = tid >> 6, l = tid & 63;
  int wr = w >> 1, wc = w & 1;
  const bf16_t* bsrc = wtb + blockIdx.y * 32768;
#pragma unroll
  for (int r = 0; r < 16; ++r) {
    int s = (r * 4 + w) * 64 + l;
    gload_lds16(bsrc + s * 8, bs + s * 8);
  }
  bf16x8 a[16];
  {
    const bf16_t* ap = xb + (rb + wr * 32 + (l & 31)) * 256 + (l >> 5) * 8;
#pragma unroll
    for (int ks = 0; ks < 16; ++ks) a[ks] = *reinterpret_cast<const bf16x8*>(ap + ks * 16);
  }
  __syncthreads();
  float scale = 20.f / mean_norm[0];
  int hi = l >> 5;
#pragma unroll
  for (int cf = 0; cf < 2; ++cf) {
    f32x16 acc = {0.f,0.f,0.f,0.f,0.f,0.f,0.f,0.f,0.f,0.f,0.f,0.f,0.f,0.f,0.f,0.f};
#pragma unroll
    for (int ks = 0; ks < 16; ++ks) {
      bf16x8 b = *reinterpret_cast<const bf16x8*>(bs + ((wc * 2 + cf) * 16 + ks) * 512 + l * 8);
      acc = __builtin_amdgcn_mfma_f32_32x32x16_bf16(a[ks], b, acc, 0, 0, 0);
    }
    int col = cbase + wc * 64 + cf * 32 + (l & 31);
    int q = col >> 8, d = col & 255;
    float bias = conv_b[d], mn = mean[d];
    int qi = q >> 1, qj = q & 1;
#pragma unroll
    for (int r = 0; r < 16; ++r) {
      int p3 = rb + wr * 32 + (r & 3) + 8 * (r >> 2) + 4 * hi;
      int n = p3 / PIX, hw = p3 % PIX;
      int h = hw / 14, ww = hw % 14;
      int p = n * 784 + (2 * h + qi) * 28 + 2 * ww + qj;
      float v = fmaxf(acc[r] + bias, 0.f);
      fb[p * 256 + d] = (bf16_t)((v - mn) * scale);
    }
  }
}

// ---- e_f[p] = exp(-||f_p||^2/(2s^2)) from rounded bf16 ----
__global__ __launch_bounds__(256) void k_ef(const bf16_t* __restrict__ fb,
                                            const float* __restrict__ sigma,
                                            float* __restrict__ e_f) {
  int lane = threadIdx.x & 63;
  int row = blockIdx.x * 4 + (threadIdx.x >> 6);
  bf16x4 h = *reinterpret_cast<const bf16x4*>(fb + row * 256 + lane * 4);
  float sq = 0.f;
#pragma unroll
  for (int i = 0; i < 4; ++i) {
    float fv = (float)h[i];
    sq += fv * fv;
  }
#pragma unroll
  for (int o = 1; o < 64; o <<= 1) sq += __shfl_xor(sq, o);
  if (lane == 0) {
    float s = sigma[0];
    e_f[row] = __expf(-sq / (2.f * s * s));
  }
}

// ---- main: 2-deep LDS ring (34 KB -> 4 blocks/CU), counted vmcnt, setprio ----
__global__ __launch_bounds__(256, 4) void k_falkon(const bf16_t* __restrict__ fb,
                                                   const float* __restrict__ e_f,
                                                   const bf16_t* __restrict__ nys,
                                                   const float* __restrict__ e_n,
                                                   const float* __restrict__ sigma,
                                                   float* __restrict__ out) {
  __shared__ bf16_t bs[2][8192];   // 2 x 16 KB ring
  __shared__ float lds_en[512];
  int c = blockIdx.y, pb = blockIdx.x * 256;
  int tid = threadIdx.x, w = tid >> 6, l = tid & 63;

  // background column (c==0 blocks); retires before the prologue counted wait
  if (c == 0) {
    int p = pb + tid;
    int n = p / 784, pix = p % 784;
    out[n * 16464 + pix] = -2.0f;
  }

  lds_en[tid] = e_n[c * M_ + tid];
  lds_en[256 + tid] = e_n[c * M_ + 256 + tid];

  // A frags: wave w rows pb + w*64 + fr*32 + (l&31); k = ks*16 + (l>>5)*8 + j
  bf16x8 a0[16], a1[16];
  {
    const bf16_t* ap0 = fb + (pb + w * 64 + (l & 31)) * 256 + (l >> 5) * 8;
    const bf16_t* ap1 = ap0 + 32 * 256;
#pragma unroll
    for (int ks = 0; ks < 16; ++ks) {
      a0[ks] = *reinterpret_cast<const bf16x8*>(ap0 + ks * 16);
      a1[ks] = *reinterpret_cast<const bf16x8*>(ap1 + ks * 16);
    }
  }

  float s = sigma[0];
  float kl = 1.44269504088896340736f / (s * s);   // log2(e)/sigma^2
  f32x16 sacc0 = {0.f,0.f,0.f,0.f,0.f,0.f,0.f,0.f,0.f,0.f,0.f,0.f,0.f,0.f,0.f,0.f};
  f32x16 sacc1 = sacc0;

  const bf16_t* nb = nys + c * (16 * 8192);

  auto stage = [&](int t) {
    const bf16_t* src = nb + t * 8192;
    bf16_t* dst = &bs[t & 1][0];
#pragma unroll
    for (int r = 0; r < 4; ++r) {
      int slot = (r * 4 + w) * 64 + l;
      gload_lds16(src + slot * 8, dst + slot * 8);
    }
  };

  // prologue: stage 0,1; wait stage(0) landed (stage(1)'s 4 loads stay in flight)
  stage(0);
  stage(1);
  asm volatile("s_waitcnt vmcnt(4) lgkmcnt(0)" ::: "memory");
  __builtin_amdgcn_s_barrier();

  for (int t = 0; t < 16; ++t) {
    f32x16 acc0 = {0.f,0.f,0.f,0.f,0.f,0.f,0.f,0.f,0.f,0.f,0.f,0.f,0.f,0.f,0.f,0.f};
    f32x16 acc1 = acc0;
    const bf16_t* bp = &bs[t & 1][0] + l * 8;
    __builtin_amdgcn_s_setprio(1);
#pragma unroll
    for (int ks = 0; ks < 16; ++ks) {
      bf16x8 b = *reinterpret_cast<const bf16x8*>(bp + ks * 512);
      acc0 = __builtin_amdgcn_mfma_f32_32x32x16_bf16(a0[ks], b, acc0, 0, 0, 0);
      acc1 = __builtin_amdgcn_mfma_f32_32x32x16_bf16(a1[ks], b, acc1, 0, 0, 0);
    }
    __builtin_amdgcn_s_setprio(0);
    float en = lds_en[t * 32 + (l & 31)];
#pragma unroll
    for (int r = 0; r < 16; ++r) {
      sacc0[r] += en * __builtin_amdgcn_exp2f(acc0[r] * kl);
      sacc1[r] += en * __builtin_amdgcn_exp2f(acc1[r] * kl);
    }
    if (t < 15) {
      asm volatile("s_waitcnt lgkmcnt(0)" ::: "memory");
      __builtin_amdgcn_s_barrier();            // all waves done reading bs[t&1]
      if (t + 2 < 16) {
        stage(t + 2);                          // into the buffer just freed
        asm volatile("s_waitcnt vmcnt(4)" ::: "memory");  // stage(t+1) landed; t+2 in flight
      } else {
        asm volatile("s_waitcnt vmcnt(0)" ::: "memory");  // tail: only stage(15) left
      }
      __builtin_amdgcn_s_barrier();            // bs[(t+1)&1] ready
    }
  }

  // reduce over 32 m-lanes within each half-wave; lanes 0 and 32 write
#pragma unroll
  for (int fr = 0; fr < 2; ++fr) {
#pragma unroll
    for (int r = 0; r < 16; ++r) {
      float v = (fr == 0) ? sacc0[r] : sacc1[r];
      v += __shfl_xor(v, 1);
      v += __shfl_xor(v, 2);
      v += __shfl_xor(v, 4);
      v += __shfl_xor(v, 8);
      v += __shfl_xor(v, 16);
      if ((l & 31) == 0) {
        int p = pb + w * 64 + fr * 32 + (r & 3) + 8 * (r >> 2) + 4 * (l >> 5);
        float score = v * e_f[p];
        int n = p / 784, pix = p % 784;
        out[n * 16464 + (c + 1) * 784 + pix] = score;
      }
    }
  }
}

extern "C" void kernel_launch(void* const* d_in, const int* in_sizes, int n_in,
                              void* d_out, int out_size, void* d_ws, size_t ws_size,
                              hipStream_t stream) {
  const float* x         = (const float*)d_in[0];
  const float* conv_w    = (const float*)d_in[1];
  const float* conv_b    = (const float*)d_in[2];
  const float* mean      = (const float*)d_in[3];
  const float* mean_norm = (const float*)d_in[4];
  const float* ny        = (const float*)d_in[5];
  const float* alpha     = (const float*)d_in[6];
  const float* sigma     = (const float*)d_in[7];
  float* out = (float*)d_out;

  char* ws = (char*)d_ws;
  bf16_t* wtb = (bf16_t*)ws;                    //   524,288 B
  bf16_t* xb  = (bf16_t*)(ws + 524288);         // 1,605,632 B
  bf16_t* fb  = (bf16_t*)(ws + 2129920);        // 6,422,528 B
  float*  e_f = (float*)(ws + 8552448);         //    50,176 B
  bf16_t* nys = (bf16_t*)(ws + 8602624);        // 5,242,880 B
  float*  e_n = (float*)(ws + 13845504);        //    40,960 B

  k_wtb<<<dim3(256), dim3(256), 0, stream>>>(conv_w, wtb);
  k_xt<<<dim3(16, 4), dim3(256), 0, stream>>>(x, xb);
  k_nyprep<<<dim3(2560), dim3(256), 0, stream>>>(ny, alpha, sigma, nys, e_n);
  k_convT<<<dim3(49, 8), dim3(256), 0, stream>>>(xb, wtb, conv_b, mean, mean_norm, fb);
  k_ef<<<dim3(3136), dim3(256), 0, stream>>>(fb, sigma, e_f);
  k_falkon<<<dim3(49, 20), dim3(256), 0, stream>>>(fb, e_f, nys, e_n, sigma, out);
}

// Round 7
// 228.884 us; speedup vs baseline: 1.2623x; 1.2623x over previous
//
#include <hip/hip_runtime.h>

typedef __bf16 bf16_t;
typedef __bf16 bf16x8 __attribute__((ext_vector_type(8)));
typedef __bf16 bf16x4 __attribute__((ext_vector_type(4)));
typedef float  f32x4  __attribute__((ext_vector_type(4)));
typedef float  f32x16 __attribute__((ext_vector_type(16)));

#define PIX 196      // 14*14
#define P_  12544    // 16*28*28
#define M_  512

__device__ inline void gload_lds16(const void* g, void* l) {
  __builtin_amdgcn_global_load_lds((const __attribute__((address_space(1))) void*)g,
                                   (__attribute__((address_space(3))) void*)l,
                                   16, 0, 0);
}

// ---- conv_w [c][d][2][2] fp32 -> wtb bf16, fragment-native ----
__global__ __launch_bounds__(256) void k_wtb(const float* __restrict__ conv_w,
                                             bf16_t* __restrict__ wtb) {
  int c = blockIdx.x, d = threadIdx.x;
  f32x4 w = *reinterpret_cast<const f32x4*>(conv_w + (c * 256 + d) * 4);
  int ks = c >> 4, kb = (c >> 3) & 1, j = c & 7;
#pragma unroll
  for (int q = 0; q < 4; ++q) {
    int col = q * 256 + d;
    int cf = col >> 5;
    int lfrag = kb * 32 + (col & 31);
    wtb[((cf * 16 + ks) * 64 + lfrag) * 8 + j] = (bf16_t)w[q];
  }
}

// ---- x[n][c][hw] fp32 -> xb[p3=n*196+hw][c] bf16 (transpose via LDS) ----
__global__ __launch_bounds__(256) void k_xt(const float* __restrict__ x,
                                            bf16_t* __restrict__ xb) {
  __shared__ float xs[64][198];
  int n = blockIdx.x, c0 = blockIdx.y * 64;
  int t = threadIdx.x;
  const float* xp = x + (n * 256 + c0) * PIX;
#pragma unroll 7
  for (int r = 0; r < 49; ++r) {
    int idx = r * 256 + t;
    xs[idx / PIX][idx % PIX] = xp[idx];
  }
  __syncthreads();
  for (int r = 0; r < 13; ++r) {
    int idx = r * 256 + t;
    if (idx < 3136) {
      int hw = idx >> 4, c4 = idx & 15;
      bf16x4 h;
#pragma unroll
      for (int i = 0; i < 4; ++i) h[i] = (bf16_t)xs[c4 * 4 + i][hw];
      *reinterpret_cast<bf16x4*>(xb + (n * PIX + hw) * 256 + c0 + c4 * 4) = h;
    }
  }
}

// ---- ny -> fragment/LDS-native bf16 chunks + e_n = exp(-||ny||^2/2s^2)*alpha ----
__global__ __launch_bounds__(256) void k_nyprep(const float* __restrict__ ny,
                                                const float* __restrict__ alpha,
                                                const float* __restrict__ sigma,
                                                bf16_t* __restrict__ nys,
                                                float* __restrict__ e_n) {
  int l = threadIdx.x & 63;
  int row = blockIdx.x * 4 + (threadIdx.x >> 6);   // c*512+m, < 10240
  int c = row >> 9, m = row & 511;
  f32x4 v = *reinterpret_cast<const f32x4*>(ny + row * 256 + l * 4);
  bf16x4 h;
  float sq = 0.f;
#pragma unroll
  for (int i = 0; i < 4; ++i) {
    h[i] = (bf16_t)v[i];
    float fv = (float)h[i];
    sq += fv * fv;
  }
  int t = m >> 5, mr = m & 31;
  int ks = l >> 2, kb = (l >> 1) & 1, j0 = (l & 1) * 4;
  *reinterpret_cast<bf16x4*>(nys + ((c * 16 + t) * 16 + ks) * 512 + (kb * 32 + mr) * 8 + j0) = h;
#pragma unroll
  for (int o = 1; o < 64; o <<= 1) sq += __shfl_xor(sq, o);
  if (l == 0) {
    float s = sigma[0];
    e_n[row] = __expf(-sq / (2.f * s * s)) * alpha[row];
  }
}

// ---- conv as GEMM ----
__global__ __launch_bounds__(256) void k_convT(const bf16_t* __restrict__ xb,
                                               const bf16_t* __restrict__ wtb,
                                               const float* __restrict__ conv_b,
                                               const float* __restrict__ mean,
                                               const float* __restrict__ mean_norm,
                                               bf16_t* __restrict__ fb) {
  __shared__ bf16_t bs[32768];
  int rb = blockIdx.x * 64, cbase = blockIdx.y * 128;
  int tid = threadIdx.x, w = tid >> 6, l = tid & 63;
  int wr = w >> 1, wc = w & 1;
  const bf16_t* bsrc = wtb + blockIdx.y * 32768;
#pragma unroll
  for (int r = 0; r < 16; ++r) {
    int s = (r * 4 + w) * 64 + l;
    gload_lds16(bsrc + s * 8, bs + s * 8);
  }
  bf16x8 a[16];
  {
    const bf16_t* ap = xb + (rb + wr * 32 + (l & 31)) * 256 + (l >> 5) * 8;
#pragma unroll
    for (int ks = 0; ks < 16; ++ks) a[ks] = *reinterpret_cast<const bf16x8*>(ap + ks * 16);
  }
  __syncthreads();
  float scale = 20.f / mean_norm[0];
  int hi = l >> 5;
#pragma unroll
  for (int cf = 0; cf < 2; ++cf) {
    f32x16 acc = {0.f,0.f,0.f,0.f,0.f,0.f,0.f,0.f,0.f,0.f,0.f,0.f,0.f,0.f,0.f,0.f};
#pragma unroll
    for (int ks = 0; ks < 16; ++ks) {
      bf16x8 b = *reinterpret_cast<const bf16x8*>(bs + ((wc * 2 + cf) * 16 + ks) * 512 + l * 8);
      acc = __builtin_amdgcn_mfma_f32_32x32x16_bf16(a[ks], b, acc, 0, 0, 0);
    }
    int col = cbase + wc * 64 + cf * 32 + (l & 31);
    int q = col >> 8, d = col & 255;
    float bias = conv_b[d], mn = mean[d];
    int qi = q >> 1, qj = q & 1;
#pragma unroll
    for (int r = 0; r < 16; ++r) {
      int p3 = rb + wr * 32 + (r & 3) + 8 * (r >> 2) + 4 * hi;
      int n = p3 / PIX, hw = p3 % PIX;
      int h = hw / 14, ww = hw % 14;
      int p = n * 784 + (2 * h + qi) * 28 + 2 * ww + qj;
      float v = fmaxf(acc[r] + bias, 0.f);
      fb[p * 256 + d] = (bf16_t)((v - mn) * scale);
    }
  }
}

// ---- e_f[p] = exp(-||f_p||^2/(2s^2)) from rounded bf16 ----
__global__ __launch_bounds__(256) void k_ef(const bf16_t* __restrict__ fb,
                                            const float* __restrict__ sigma,
                                            float* __restrict__ e_f) {
  int lane = threadIdx.x & 63;
  int row = blockIdx.x * 4 + (threadIdx.x >> 6);
  bf16x4 h = *reinterpret_cast<const bf16x4*>(fb + row * 256 + lane * 4);
  float sq = 0.f;
#pragma unroll
  for (int i = 0; i < 4; ++i) {
    float fv = (float)h[i];
    sq += fv * fv;
  }
#pragma unroll
  for (int o = 1; o < 64; o <<= 1) sq += __shfl_xor(sq, o);
  if (lane == 0) {
    float s = sigma[0];
    e_f[row] = __expf(-sq / (2.f * s * s));
  }
}

// ---- main: 2-deep LDS ring (34 KB), counted vmcnt, 3 waves/SIMD (no spill) ----
__global__ __launch_bounds__(256, 3) void k_falkon(const bf16_t* __restrict__ fb,
                                                   const float* __restrict__ e_f,
                                                   const bf16_t* __restrict__ nys,
                                                   const float* __restrict__ e_n,
                                                   const float* __restrict__ sigma,
                                                   float* __restrict__ out) {
  __shared__ bf16_t bs[2][8192];   // 2 x 16 KB ring
  __shared__ float lds_en[512];
  int c = blockIdx.y, pb = blockIdx.x * 256;
  int tid = threadIdx.x, w = tid >> 6, l = tid & 63;

  // background column (c==0 blocks); retires before the prologue counted wait
  if (c == 0) {
    int p = pb + tid;
    int n = p / 784, pix = p % 784;
    out[n * 16464 + pix] = -2.0f;
  }

  lds_en[tid] = e_n[c * M_ + tid];
  lds_en[256 + tid] = e_n[c * M_ + 256 + tid];

  // A frags: wave w rows pb + w*64 + fr*32 + (l&31); k = ks*16 + (l>>5)*8 + j
  bf16x8 a0[16], a1[16];
  {
    const bf16_t* ap0 = fb + (pb + w * 64 + (l & 31)) * 256 + (l >> 5) * 8;
    const bf16_t* ap1 = ap0 + 32 * 256;
#pragma unroll
    for (int ks = 0; ks < 16; ++ks) {
      a0[ks] = *reinterpret_cast<const bf16x8*>(ap0 + ks * 16);
      a1[ks] = *reinterpret_cast<const bf16x8*>(ap1 + ks * 16);
    }
  }

  float s = sigma[0];
  float kl = 1.44269504088896340736f / (s * s);   // log2(e)/sigma^2
  f32x16 sacc0 = {0.f,0.f,0.f,0.f,0.f,0.f,0.f,0.f,0.f,0.f,0.f,0.f,0.f,0.f,0.f,0.f};
  f32x16 sacc1 = sacc0;

  const bf16_t* nb = nys + c * (16 * 8192);

  auto stage = [&](int t) {
    const bf16_t* src = nb + t * 8192;
    bf16_t* dst = &bs[t & 1][0];
#pragma unroll
    for (int r = 0; r < 4; ++r) {
      int slot = (r * 4 + w) * 64 + l;
      gload_lds16(src + slot * 8, dst + slot * 8);
    }
  };

  // prologue: stage 0,1; wait stage(0) landed (stage(1)'s 4 loads stay in flight)
  stage(0);
  stage(1);
  asm volatile("s_waitcnt vmcnt(4) lgkmcnt(0)" ::: "memory");
  __builtin_amdgcn_s_barrier();

  for (int t = 0; t < 16; ++t) {
    f32x16 acc0 = {0.f,0.f,0.f,0.f,0.f,0.f,0.f,0.f,0.f,0.f,0.f,0.f,0.f,0.f,0.f,0.f};
    f32x16 acc1 = acc0;
    const bf16_t* bp = &bs[t & 1][0] + l * 8;
    __builtin_amdgcn_s_setprio(1);
#pragma unroll
    for (int ks = 0; ks < 16; ++ks) {
      bf16x8 b = *reinterpret_cast<const bf16x8*>(bp + ks * 512);
      acc0 = __builtin_amdgcn_mfma_f32_32x32x16_bf16(a0[ks], b, acc0, 0, 0, 0);
      acc1 = __builtin_amdgcn_mfma_f32_32x32x16_bf16(a1[ks], b, acc1, 0, 0, 0);
    }
    __builtin_amdgcn_s_setprio(0);
    float en = lds_en[t * 32 + (l & 31)];
#pragma unroll
    for (int r = 0; r < 16; ++r) {
      sacc0[r] += en * __builtin_amdgcn_exp2f(acc0[r] * kl);
      sacc1[r] += en * __builtin_amdgcn_exp2f(acc1[r] * kl);
    }
    if (t < 15) {
      asm volatile("s_waitcnt lgkmcnt(0)" ::: "memory");
      __builtin_amdgcn_s_barrier();            // all waves done reading bs[t&1]
      if (t + 2 < 16) {
        stage(t + 2);                          // into the buffer just freed
        asm volatile("s_waitcnt vmcnt(4)" ::: "memory");  // stage(t+1) landed; t+2 in flight
      } else {
        asm volatile("s_waitcnt vmcnt(0)" ::: "memory");  // tail: only stage(15) left
      }
      __builtin_amdgcn_s_barrier();            // bs[(t+1)&1] ready
    }
  }

  // reduce over 32 m-lanes within each half-wave; lanes 0 and 32 write
#pragma unroll
  for (int fr = 0; fr < 2; ++fr) {
#pragma unroll
    for (int r = 0; r < 16; ++r) {
      float v = (fr == 0) ? sacc0[r] : sacc1[r];
      v += __shfl_xor(v, 1);
      v += __shfl_xor(v, 2);
      v += __shfl_xor(v, 4);
      v += __shfl_xor(v, 8);
      v += __shfl_xor(v, 16);
      if ((l & 31) == 0) {
        int p = pb + w * 64 + fr * 32 + (r & 3) + 8 * (r >> 2) + 4 * (l >> 5);
        float score = v * e_f[p];
        int n = p / 784, pix = p % 784;
        out[n * 16464 + (c + 1) * 784 + pix] = score;
      }
    }
  }
}

extern "C" void kernel_launch(void* const* d_in, const int* in_sizes, int n_in,
                              void* d_out, int out_size, void* d_ws, size_t ws_size,
                              hipStream_t stream) {
  const float* x         = (const float*)d_in[0];
  const float* conv_w    = (const float*)d_in[1];
  const float* conv_b    = (const float*)d_in[2];
  const float* mean      = (const float*)d_in[3];
  const float* mean_norm = (const float*)d_in[4];
  const float* ny        = (const float*)d_in[5];
  const float* alpha     = (const float*)d_in[6];
  const float* sigma     = (const float*)d_in[7];
  float* out = (float*)d_out;

  char* ws = (char*)d_ws;
  bf16_t* wtb = (bf16_t*)ws;                    //   524,288 B
  bf16_t* xb  = (bf16_t*)(ws + 524288);         // 1,605,632 B
  bf16_t* fb  = (bf16_t*)(ws + 2129920);        // 6,422,528 B
  float*  e_f = (float*)(ws + 8552448);         //    50,176 B
  bf16_t* nys = (bf16_t*)(ws + 8602624);        // 5,242,880 B
  float*  e_n = (float*)(ws + 13845504);        //    40,960 B

  k_wtb<<<dim3(256), dim3(256), 0, stream>>>(conv_w, wtb);
  k_xt<<<dim3(16, 4), dim3(256), 0, stream>>>(x, xb);
  k_nyprep<<<dim3(2560), dim3(256), 0, stream>>>(ny, alpha, sigma, nys, e_n);
  k_convT<<<dim3(49, 8), dim3(256), 0, stream>>>(xb, wtb, conv_b, mean, mean_norm, fb);
  k_ef<<<dim3(3136), dim3(256), 0, stream>>>(fb, sigma, e_f);
  k_falkon<<<dim3(49, 20), dim3(256), 0, stream>>>(fb, e_f, nys, e_n, sigma, out);
}

// Round 8
// 112.383 us; speedup vs baseline: 2.5708x; 2.0366x over previous
//
#include <hip/hip_runtime.h>

typedef __bf16 bf16_t;
typedef __bf16 bf16x8 __attribute__((ext_vector_type(8)));
typedef __bf16 bf16x4 __attribute__((ext_vector_type(4)));
typedef float  f32x4  __attribute__((ext_vector_type(4)));
typedef float  f32x16 __attribute__((ext_vector_type(16)));

#define PIX 196      // 14*14
#define P_  12544    // 16*28*28
#define M_  512

__device__ inline void gload_lds16(const void* g, void* l) {
  __builtin_amdgcn_global_load_lds((const __attribute__((address_space(1))) void*)g,
                                   (__attribute__((address_space(3))) void*)l,
                                   16, 0, 0);
}

// ---- conv_w [c][d][2][2] fp32 -> wtb bf16, fragment-native ----
__global__ __launch_bounds__(256) void k_wtb(const float* __restrict__ conv_w,
                                             bf16_t* __restrict__ wtb) {
  int c = blockIdx.x, d = threadIdx.x;
  f32x4 w = *reinterpret_cast<const f32x4*>(conv_w + (c * 256 + d) * 4);
  int ks = c >> 4, kb = (c >> 3) & 1, j = c & 7;
#pragma unroll
  for (int q = 0; q < 4; ++q) {
    int col = q * 256 + d;
    int cf = col >> 5;
    int lfrag = kb * 32 + (col & 31);
    wtb[((cf * 16 + ks) * 64 + lfrag) * 8 + j] = (bf16_t)w[q];
  }
}

// ---- x[n][c][hw] fp32 -> xb[p3=n*196+hw][c] bf16 (transpose via LDS) ----
__global__ __launch_bounds__(256) void k_xt(const float* __restrict__ x,
                                            bf16_t* __restrict__ xb) {
  __shared__ float xs[64][198];
  int n = blockIdx.x, c0 = blockIdx.y * 64;
  int t = threadIdx.x;
  const float* xp = x + (n * 256 + c0) * PIX;
#pragma unroll 7
  for (int r = 0; r < 49; ++r) {
    int idx = r * 256 + t;
    xs[idx / PIX][idx % PIX] = xp[idx];
  }
  __syncthreads();
  for (int r = 0; r < 13; ++r) {
    int idx = r * 256 + t;
    if (idx < 3136) {
      int hw = idx >> 4, c4 = idx & 15;
      bf16x4 h;
#pragma unroll
      for (int i = 0; i < 4; ++i) h[i] = (bf16_t)xs[c4 * 4 + i][hw];
      *reinterpret_cast<bf16x4*>(xb + (n * PIX + hw) * 256 + c0 + c4 * 4) = h;
    }
  }
}

// ---- ny -> fragment/LDS-native bf16 chunks + e_n = exp(-||ny||^2/2s^2)*alpha ----
__global__ __launch_bounds__(256) void k_nyprep(const float* __restrict__ ny,
                                                const float* __restrict__ alpha,
                                                const float* __restrict__ sigma,
                                                bf16_t* __restrict__ nys,
                                                float* __restrict__ e_n) {
  int l = threadIdx.x & 63;
  int row = blockIdx.x * 4 + (threadIdx.x >> 6);   // c*512+m, < 10240
  int c = row >> 9, m = row & 511;
  f32x4 v = *reinterpret_cast<const f32x4*>(ny + row * 256 + l * 4);
  bf16x4 h;
  float sq = 0.f;
#pragma unroll
  for (int i = 0; i < 4; ++i) {
    h[i] = (bf16_t)v[i];
    float fv = (float)h[i];
    sq += fv * fv;
  }
  int t = m >> 5, mr = m & 31;
  int ks = l >> 2, kb = (l >> 1) & 1, j0 = (l & 1) * 4;
  *reinterpret_cast<bf16x4*>(nys + ((c * 16 + t) * 16 + ks) * 512 + (kb * 32 + mr) * 8 + j0) = h;
#pragma unroll
  for (int o = 1; o < 64; o <<= 1) sq += __shfl_xor(sq, o);
  if (l == 0) {
    float s = sigma[0];
    e_n[row] = __expf(-sq / (2.f * s * s)) * alpha[row];
  }
}

// ---- conv as GEMM ----
__global__ __launch_bounds__(256) void k_convT(const bf16_t* __restrict__ xb,
                                               const bf16_t* __restrict__ wtb,
                                               const float* __restrict__ conv_b,
                                               const float* __restrict__ mean,
                                               const float* __restrict__ mean_norm,
                                               bf16_t* __restrict__ fb) {
  __shared__ bf16_t bs[32768];
  int rb = blockIdx.x * 64, cbase = blockIdx.y * 128;
  int tid = threadIdx.x, w = tid >> 6, l = tid & 63;
  int wr = w >> 1, wc = w & 1;
  const bf16_t* bsrc = wtb + blockIdx.y * 32768;
#pragma unroll
  for (int r = 0; r < 16; ++r) {
    int s = (r * 4 + w) * 64 + l;
    gload_lds16(bsrc + s * 8, bs + s * 8);
  }
  bf16x8 a[16];
  {
    const bf16_t* ap = xb + (rb + wr * 32 + (l & 31)) * 256 + (l >> 5) * 8;
#pragma unroll
    for (int ks = 0; ks < 16; ++ks) a[ks] = *reinterpret_cast<const bf16x8*>(ap + ks * 16);
  }
  __syncthreads();
  float scale = 20.f / mean_norm[0];
  int hi = l >> 5;
#pragma unroll
  for (int cf = 0; cf < 2; ++cf) {
    f32x16 acc = {0.f,0.f,0.f,0.f,0.f,0.f,0.f,0.f,0.f,0.f,0.f,0.f,0.f,0.f,0.f,0.f};
#pragma unroll
    for (int ks = 0; ks < 16; ++ks) {
      bf16x8 b = *reinterpret_cast<const bf16x8*>(bs + ((wc * 2 + cf) * 16 + ks) * 512 + l * 8);
      acc = __builtin_amdgcn_mfma_f32_32x32x16_bf16(a[ks], b, acc, 0, 0, 0);
    }
    int col = cbase + wc * 64 + cf * 32 + (l & 31);
    int q = col >> 8, d = col & 255;
    float bias = conv_b[d], mn = mean[d];
    int qi = q >> 1, qj = q & 1;
#pragma unroll
    for (int r = 0; r < 16; ++r) {
      int p3 = rb + wr * 32 + (r & 3) + 8 * (r >> 2) + 4 * hi;
      int n = p3 / PIX, hw = p3 % PIX;
      int h = hw / 14, ww = hw % 14;
      int p = n * 784 + (2 * h + qi) * 28 + 2 * ww + qj;
      float v = fmaxf(acc[r] + bias, 0.f);
      fb[p * 256 + d] = (bf16_t)((v - mn) * scale);
    }
  }
}

// ---- main: 32 rows/wave (block=128p), 2-deep ring, counted vmcnt, fused e_f ----
__global__ __launch_bounds__(256, 3) void k_falkon(const bf16_t* __restrict__ fb,
                                                   const bf16_t* __restrict__ nys,
                                                   const float* __restrict__ e_n,
                                                   const float* __restrict__ sigma,
                                                   float* __restrict__ out) {
  __shared__ bf16_t bs[2][8192];   // 2 x 16 KB ring
  __shared__ float lds_en[512];
  int c = blockIdx.y, pb = blockIdx.x * 128;
  int tid = threadIdx.x, w = tid >> 6, l = tid & 63;

  // background column (c==0 blocks); retires before the prologue counted wait
  if (c == 0 && tid < 128) {
    int p = pb + tid;
    out[(p / 784) * 16464 + (p % 784)] = -2.0f;
  }

  lds_en[tid] = e_n[c * M_ + tid];
  lds_en[256 + tid] = e_n[c * M_ + 256 + tid];

  // A frags: wave w rows pb + w*32 + (l&31); k = ks*16 + (l>>5)*8 + j
  bf16x8 a[16];
  {
    const bf16_t* ap = fb + (pb + w * 32 + (l & 31)) * 256 + (l >> 5) * 8;
#pragma unroll
    for (int ks = 0; ks < 16; ++ks) a[ks] = *reinterpret_cast<const bf16x8*>(ap + ks * 16);
  }

  float s = sigma[0];
  float kl = 1.44269504088896340736f / (s * s);   // log2(e)/sigma^2

  // fused e_f: ||f_row||^2 from the bf16 fragments (lane pair l, l+32 holds the row)
  float ss = 0.f;
#pragma unroll
  for (int ks = 0; ks < 16; ++ks)
#pragma unroll
    for (int j = 0; j < 8; ++j) {
      float fv = (float)a[ks][j];
      ss += fv * fv;
    }
  ss += __shfl_xor(ss, 32);
  float ef_reg = __builtin_amdgcn_exp2f(ss * (-0.5f * kl));   // lane (l&31) holds row w*32+(l&31)

  f32x16 sacc = {0.f,0.f,0.f,0.f,0.f,0.f,0.f,0.f,0.f,0.f,0.f,0.f,0.f,0.f,0.f,0.f};

  const bf16_t* nb = nys + c * (16 * 8192);

  auto stage = [&](int t) {
    const bf16_t* src = nb + t * 8192;
    bf16_t* dst = &bs[t & 1][0];
#pragma unroll
    for (int r = 0; r < 4; ++r) {
      int slot = (r * 4 + w) * 64 + l;
      gload_lds16(src + slot * 8, dst + slot * 8);
    }
  };

  // prologue: stage 0,1; wait stage(0) landed (stage(1)'s 4 loads stay in flight)
  stage(0);
  stage(1);
  asm volatile("s_waitcnt vmcnt(4) lgkmcnt(0)" ::: "memory");
  __builtin_amdgcn_s_barrier();

  for (int t = 0; t < 16; ++t) {
    f32x16 acc = {0.f,0.f,0.f,0.f,0.f,0.f,0.f,0.f,0.f,0.f,0.f,0.f,0.f,0.f,0.f,0.f};
    const bf16_t* bp = &bs[t & 1][0] + l * 8;
    __builtin_amdgcn_s_setprio(1);
#pragma unroll
    for (int ks = 0; ks < 16; ++ks) {
      bf16x8 b = *reinterpret_cast<const bf16x8*>(bp + ks * 512);
      acc = __builtin_amdgcn_mfma_f32_32x32x16_bf16(a[ks], b, acc, 0, 0, 0);
    }
    __builtin_amdgcn_s_setprio(0);
    float en = lds_en[t * 32 + (l & 31)];
#pragma unroll
    for (int r = 0; r < 16; ++r)
      sacc[r] += en * __builtin_amdgcn_exp2f(acc[r] * kl);
    if (t < 15) {
      asm volatile("s_waitcnt lgkmcnt(0)" ::: "memory");
      __builtin_amdgcn_s_barrier();            // all waves done reading bs[t&1]
      if (t + 2 < 16) {
        stage(t + 2);                          // into the buffer just freed
        asm volatile("s_waitcnt vmcnt(4)" ::: "memory");  // stage(t+1) landed; t+2 in flight
      } else {
        asm volatile("s_waitcnt vmcnt(0)" ::: "memory");  // tail: only stage(15) left
      }
      __builtin_amdgcn_s_barrier();            // bs[(t+1)&1] ready
    }
  }

  // reduce over 32 m-lanes; apply e_f via shfl; lanes 0,32 write
#pragma unroll
  for (int r = 0; r < 16; ++r) {
    float v = sacc[r];
    v += __shfl_xor(v, 1);
    v += __shfl_xor(v, 2);
    v += __shfl_xor(v, 4);
    v += __shfl_xor(v, 8);
    v += __shfl_xor(v, 16);
    int row = (r & 3) + 8 * (r >> 2) + 4 * (l >> 5);   // 0..31 within wave tile
    float ef = __shfl(ef_reg, row);                    // from lane `row`
    if ((l & 31) == 0) {
      int p = pb + w * 32 + row;
      out[(p / 784) * 16464 + (c + 1) * 784 + (p % 784)] = v * ef;
    }
  }
}

extern "C" void kernel_launch(void* const* d_in, const int* in_sizes, int n_in,
                              void* d_out, int out_size, void* d_ws, size_t ws_size,
                              hipStream_t stream) {
  const float* x         = (const float*)d_in[0];
  const float* conv_w    = (const float*)d_in[1];
  const float* conv_b    = (const float*)d_in[2];
  const float* mean      = (const float*)d_in[3];
  const float* mean_norm = (const float*)d_in[4];
  const float* ny        = (const float*)d_in[5];
  const float* alpha     = (const float*)d_in[6];
  const float* sigma     = (const float*)d_in[7];
  float* out = (float*)d_out;

  char* ws = (char*)d_ws;
  bf16_t* wtb = (bf16_t*)ws;                    //   524,288 B
  bf16_t* xb  = (bf16_t*)(ws + 524288);         // 1,605,632 B
  bf16_t* fb  = (bf16_t*)(ws + 2129920);        // 6,422,528 B
  bf16_t* nys = (bf16_t*)(ws + 8602624);        // 5,242,880 B
  float*  e_n = (float*)(ws + 13845504);        //    40,960 B

  k_wtb<<<dim3(256), dim3(256), 0, stream>>>(conv_w, wtb);
  k_xt<<<dim3(16, 4), dim3(256), 0, stream>>>(x, xb);
  k_nyprep<<<dim3(2560), dim3(256), 0, stream>>>(ny, alpha, sigma, nys, e_n);
  k_convT<<<dim3(49, 8), dim3(256), 0, stream>>>(xb, wtb, conv_b, mean, mean_norm, fb);
  k_falkon<<<dim3(98, 20), dim3(256), 0, stream>>>(fb, nys, e_n, sigma, out);
}